// Round 11
// baseline (376.647 us; speedup 1.0000x reference)
//
#include <hip/hip_runtime.h>
#include <stdint.h>

#define NB 4096
#define NS 512
#define NA 64
#define NH1 1024
#define NH2 512

typedef __attribute__((ext_vector_type(8))) short bf16x8;
typedef __attribute__((ext_vector_type(4))) float f32x4;
typedef __attribute__((ext_vector_type(16))) float f32x16;

__device__ __forceinline__ unsigned short f2bf(float f) {
    union { float f; unsigned u; } v; v.f = f;
    return (unsigned short)((v.u + 0x8000u) >> 16);   // round-half-up bf16
}
__device__ __forceinline__ float bf2f(unsigned short h) {
    union { float f; unsigned u; } v; v.u = ((unsigned)h) << 16;
    return v.f;
}
__device__ __forceinline__ float bflo(unsigned u) {
    union { unsigned u; float f; } v; v.u = u << 16; return v.f;
}
__device__ __forceinline__ float bfhi(unsigned u) {
    union { unsigned u; float f; } v; v.u = u & 0xFFFF0000u; return v.f;
}
// truncating pack of two f32 -> bf16x2 (bias cancels in u/||u||): 1 v_perm
__device__ __forceinline__ unsigned packtrunc(float lo, float hi) {
    union { float f; unsigned u; } a, b; a.f = lo; b.f = hi;
    return __builtin_amdgcn_perm(b.u, a.u, 0x07060302u);
}
__device__ __forceinline__ void split2(float x, unsigned short& h, unsigned short& l) {
    unsigned short hh = f2bf(x);
    h = hh;
    l = f2bf(x - bf2f(hh));
}

// ---------------- P0: nb[b] = sqrt(||s_b||^2 + 1) + 1e-8 ----------------
__global__ void knorm(const float* __restrict__ S, float* __restrict__ nb) {
    int b = blockIdx.x; int l = threadIdx.x; // one wave
    const float* row = S + b * NS;
    float s = 0.f;
    for (int k = l; k < NS; k += 64) { float v = row[k]; s = fmaf(v, v, s); }
    for (int off = 32; off; off >>= 1) s += __shfl_down(s, off, 64);
    if (l == 0) nb[b] = sqrtf(s + 1.0f) + 1e-8f;
}

// ---------------- P1: W2f (32x32x16 B-frag linear pack) + caT2 ----------------
// R16: W2f repacked for mfma_f32_32x32x16_bf16 B operand (col=l&31,
// k=(l>>5)*8+j). Flat idx = (((kc*32 + ks*16 + c) * 64 + l) * 8 + j):
//   value = W2[c*32 + (l&31)][kc*32 + ks*16 + (l>>5)*8 + j]
// c = global 32-col tile 0..15, ks = k-step 0..1. Per (kc,ks,c): 1 KB
// lane-linear => direct global bfr loads stay fully coalesced, no swizzle.
// Per-kc tile still 32 KB (stride 16384 shorts).
// caT2[at][kc][a_loc][kk] = W1[(kc*32+kk)*576 + 512 + at*16 + a_loc]  (unchanged)
__global__ void kprep(const float* __restrict__ W1, const float* __restrict__ W2,
                      unsigned short* __restrict__ W2f, unsigned short* __restrict__ caT2) {
    int i = blockIdx.x * 256 + threadIdx.x;
    if (i < 524288) {
        int j = i & 7; int l = (i >> 3) & 63; int u = i >> 9;   // u 0..1023
        int c = u & 15; int ks = (u >> 4) & 1; int kc = u >> 5;
        int n = c * 32 + (l & 31);
        int k = kc * 32 + ks * 16 + (l >> 5) * 8 + j;
        W2f[i] = f2bf(W2[(size_t)n * NH1 + k]);
    } else {
        int j2 = i - 524288;                 // 65536 entries
        int kk = j2 & 31; int a_loc = (j2 >> 5) & 15;
        int kc = (j2 >> 9) & 31; int att = j2 >> 14;
        int o = kc * 32 + kk;
        caT2[j2] = f2bf(W1[(size_t)o * 576 + 512 + att * 16 + a_loc]);
    }
}

// ---------------- P2: Gt'[kc][b][32k] bf16 = s@W1s^T + b1*nb  (split-bf16, 3 GEMMs) ----
// R15 (unchanged): 64x64 tiles, grid 1024 = 4 blocks/CU for cross-block cover.
__global__ __launch_bounds__(256) void kgemm1(
        const float* __restrict__ Sm, const float* __restrict__ W1,
        const float* __restrict__ b1, const float* __restrict__ nb,
        unsigned short* __restrict__ Gt) {
    const int m0 = (blockIdx.x >> 4) * 64;   // 64 M-tiles
    const int n0 = (blockIdx.x & 15) * 64;   // 16 N-tiles
    __shared__ unsigned short Ah[64][40], Al[64][40], Bh[64][40], Bl[64][40];
    int t = threadIdx.x;
    int lane = t & 63, wave = t >> 6;
    int wr = wave >> 1, wc = wave & 1;       // 2x2 waves of 32x32 tiles
    int qd = lane >> 4, cl = lane & 15;
    int r = t >> 2, seg = t & 3;             // 4 threads/row, 8 floats each
    f32x4 acc[2][2] = {};

    for (int k0 = 0; k0 < 512; k0 += 32) {
        {
            const float4* as4 = (const float4*)(Sm + (size_t)(m0 + r) * NS + k0 + seg * 8);
            const float4* bs4 = (const float4*)(W1 + (size_t)(n0 + r) * 576 + k0 + seg * 8);
            unsigned* ah = (unsigned*)&Ah[r][seg * 8];
            unsigned* al = (unsigned*)&Al[r][seg * 8];
            unsigned* bh = (unsigned*)&Bh[r][seg * 8];
            unsigned* bl = (unsigned*)&Bl[r][seg * 8];
#pragma unroll
            for (int v = 0; v < 2; v++) {
                float4 fa = as4[v];
                unsigned short h0,h1,h2,h3,l0,l1,l2,l3;
                split2(fa.x,h0,l0); split2(fa.y,h1,l1); split2(fa.z,h2,l2); split2(fa.w,h3,l3);
                ah[v*2]   = (unsigned)h0 | ((unsigned)h1 << 16);
                ah[v*2+1] = (unsigned)h2 | ((unsigned)h3 << 16);
                al[v*2]   = (unsigned)l0 | ((unsigned)l1 << 16);
                al[v*2+1] = (unsigned)l2 | ((unsigned)l3 << 16);
                float4 fb = bs4[v];
                split2(fb.x,h0,l0); split2(fb.y,h1,l1); split2(fb.z,h2,l2); split2(fb.w,h3,l3);
                bh[v*2]   = (unsigned)h0 | ((unsigned)h1 << 16);
                bh[v*2+1] = (unsigned)h2 | ((unsigned)h3 << 16);
                bl[v*2]   = (unsigned)l0 | ((unsigned)l1 << 16);
                bl[v*2+1] = (unsigned)l2 | ((unsigned)l3 << 16);
            }
        }
        __syncthreads();
        bf16x8 a_h[2], a_l[2], b_h[2], b_l[2];
#pragma unroll
        for (int mt = 0; mt < 2; mt++) {
            a_h[mt] = *(const bf16x8*)&Ah[wr*32 + mt*16 + cl][qd*8];
            a_l[mt] = *(const bf16x8*)&Al[wr*32 + mt*16 + cl][qd*8];
        }
#pragma unroll
        for (int nt = 0; nt < 2; nt++) {
            b_h[nt] = *(const bf16x8*)&Bh[wc*32 + nt*16 + cl][qd*8];
            b_l[nt] = *(const bf16x8*)&Bl[wc*32 + nt*16 + cl][qd*8];
        }
#pragma unroll
        for (int mt = 0; mt < 2; mt++)
#pragma unroll
            for (int nt = 0; nt < 2; nt++) {
                acc[mt][nt] = __builtin_amdgcn_mfma_f32_16x16x32_bf16(a_h[mt], b_h[nt], acc[mt][nt], 0, 0, 0);
                acc[mt][nt] = __builtin_amdgcn_mfma_f32_16x16x32_bf16(a_h[mt], b_l[nt], acc[mt][nt], 0, 0, 0);
                acc[mt][nt] = __builtin_amdgcn_mfma_f32_16x16x32_bf16(a_l[mt], b_h[nt], acc[mt][nt], 0, 0, 0);
            }
        __syncthreads();
    }
#pragma unroll
    for (int mt = 0; mt < 2; mt++)
#pragma unroll
        for (int i = 0; i < 4; i++) {
            int m = m0 + wr*32 + mt*16 + qd*4 + i;
            float nbv = nb[m];
#pragma unroll
            for (int nt = 0; nt < 2; nt++) {
                int n = n0 + wc*32 + nt*16 + cl;
                float val = fmaf(b1[n], nbv, acc[mt][nt][i]);
                Gt[((size_t)(n >> 5) * NB + m) * 32 + (n & 31)] = f2bf(val);
            }
        }
}

// ---------------- Main: 256 thr, 64 rows (16a x 4b) x 512 cols, K=1024, Kc=32 ----------
// R16: 32x32x16 MFMA shape. Pipe rates: 16x16x32 = 844 FLOP/cyc/SIMD (19.4
// cyc), 32x32x16 = 970 (33.8 cyc) -> per-iter matrix time 620 -> 540 cyc and
// HALF the issue slots (16 vs 32 MFMAs). Wave tile stays 64x128: 2 m-tiles x
// 4 n-tiles x 2 k-steps; acc = f32x16[2][4] (same 128 regs). A path now
// FRAG-PACKED in LDS: agen thread (row,kd) writes one b128 to
// frag((row>>5)*2+(kd>>1)) * 1KB + lane((kd&1)*32+(row&31)) * 16B; af reads
// are lane-linear (2-way-free banks) -> kills the strided-As bank conflicts
// (constant 1.26e7 all session). Ring (8 slots, window barrier every 4 iters,
// produce-lead 4) and bfr L/H register pipeline (now split on k-step)
// unchanged. Epilogue uses verified 32x32 C/D map: col=l&31,
// row=(r&3)+8*(r>>2)+4*(l>>5).
__global__ __launch_bounds__(256, 2) void kmain(
        const unsigned short* __restrict__ Gt,    // [32][4096][32]
        const unsigned short* __restrict__ caT2,  // [4][32][16][32]
        const unsigned short* __restrict__ W2f,   // per-kc 32 KB frag-packed tiles
        const float* __restrict__ nb,
        const float* __restrict__ b2, const float* __restrict__ Wq,
        const float* __restrict__ bq, float* __restrict__ out) {
    int bid = blockIdx.x;
    int at = bid & 3;
    int bt = bid >> 2;            // 0..1023, covers b rows bt*4 .. bt*4+3

    __shared__ __align__(16) unsigned short Asf[8][2048]; // ring: 4 frags x 64 x 8 shorts = 4 KB/slot
    __shared__ float invnh[64];
    __shared__ float qred[64][4];

    int t = threadIdx.x;          // 0..255
    int lane = t & 63, wc = t >> 6;   // wc = wave = col quarter (128 cols)
    int l31 = lane & 31, hi = lane >> 5;

    // A-gen role: thread owns row (t>>2), k-octet (t&3); 8 elements/iter
    int row = t >> 2, kd = t & 3;     // row 0..63
    int ab = row >> 2, bb = row & 3;  // 16 a x 4 b
    const unsigned short* gG = Gt + ((size_t)(bt * 4 + bb)) * 32 + kd * 8;
    const unsigned short* gC = caT2 + (size_t)at * 16384 + ab * 32 + kd * 8;

    float sq = 0.f;
    f32x16 acc[2][4] = {};
    bf16x8 g_v, c_v;

    // frag-packed write slot: frag = (row>>5)*2 + (kd>>1); lane slot = (kd&1)*32 + (row&31)
    const int aw = (((row >> 5) * 2 + (kd >> 1)) * 64 + ((kd & 1) * 32 + (row & 31))) * 8;

    auto agen = [&](int slot) {
        const unsigned* gd = (const unsigned*)&g_v;
        const unsigned* cd = (const unsigned*)&c_v;
        unsigned ow[4];
#pragma unroll
        for (int p = 0; p < 4; p++) {
            float u0 = fmaxf(bflo(gd[p]) + bflo(cd[p]), 0.f);
            float u1 = fmaxf(bfhi(gd[p]) + bfhi(cd[p]), 0.f);
            sq = fmaf(u0, u0, sq);
            sq = fmaf(u1, u1, sq);
            ow[p] = packtrunc(u0, u1);
        }
        *(bf16x8*)&Asf[slot][aw] = *(bf16x8*)ow;
    };

    // B frag source: lane-linear global address; frag (ks,nt) at +ks*8192 + nt*512
    const unsigned short* gB = W2f + wc * 2048 + lane * 8;

    bf16x8 bfrL[4], bfrH[4];

    // ---- prologue: produce tiles 0..3 into ring slots 0..3; leave g/c = tile 4 ----
    g_v = *(const bf16x8*)gG;
    c_v = *(const bf16x8*)gC;
#pragma unroll
    for (int p = 0; p < 4; ++p) {
        agen(p);                       // tile p -> slot p (ascending kc: sq order preserved)
        gG += (size_t)NB * 32;
        gC += 512;
        g_v = *(const bf16x8*)gG;      // tile p+1 (ends with tile 4)
        c_v = *(const bf16x8*)gC;
    }
    // bfr(kc0)
#pragma unroll
    for (int j = 0; j < 4; j++)
        bfrL[j] = *(const bf16x8*)(gB + j * 512);
#pragma unroll
    for (int j = 0; j < 4; j++)
        bfrH[j] = *(const bf16x8*)(gB + 8192 + j * 512);
    gB += 16384;

    for (int it = 0; it < 32; ++it) {
        // ---- window barrier: publish tiles produced in previous window ----
        if ((it & 3) == 0) {
            asm volatile("s_waitcnt lgkmcnt(0)" ::: "memory");  // drain own agen writes
            __builtin_amdgcn_s_barrier();
            __builtin_amdgcn_sched_barrier(0);
        }
        int rs = it & 7;

        // ---- A frags: lane-linear reads from frag-packed slot ----
        bf16x8 afL[2], afH[2];
        const unsigned short* ab2 = &Asf[rs][lane * 8];
        afL[0] = *(const bf16x8*)(ab2);          // (mt0, ks0)
        afH[0] = *(const bf16x8*)(ab2 + 512);    // (mt0, ks1)
        afL[1] = *(const bf16x8*)(ab2 + 1024);   // (mt1, ks0)
        afH[1] = *(const bf16x8*)(ab2 + 1536);   // (mt1, ks1)

        // ---- produce tile it+4 into slot (it+4)&7; prefetch g/c(it+5) ----
        if (it < 28) agen((it + 4) & 7);
        if (it < 27) {
            gG += (size_t)NB * 32;
            gC += 512;
            g_v = *(const bf16x8*)gG;
            c_v = *(const bf16x8*)gC;
        }

        // ---- MFMA on ks=0 (bfrH(kc) still draining under this) ----
        __builtin_amdgcn_s_setprio(1);
#pragma unroll
        for (int nt = 0; nt < 4; nt++)
#pragma unroll
            for (int mt = 0; mt < 2; mt++)
                acc[mt][nt] = __builtin_amdgcn_mfma_f32_32x32x16_bf16(afL[mt], bfrL[nt], acc[mt][nt], 0, 0, 0);
        __builtin_amdgcn_s_setprio(0);

        // ---- issue L'(kc+1) into L regs (WAR reuse; drains under ks=1 MFMAs) ----
        if (it < 31) {
#pragma unroll
            for (int j = 0; j < 4; j++)
                bfrL[j] = *(const bf16x8*)(gB + j * 512);
        }

        // ---- MFMA on ks=1 (L' draining under this) ----
        __builtin_amdgcn_s_setprio(1);
#pragma unroll
        for (int nt = 0; nt < 4; nt++)
#pragma unroll
            for (int mt = 0; mt < 2; mt++)
                acc[mt][nt] = __builtin_amdgcn_mfma_f32_32x32x16_bf16(afH[mt], bfrH[nt], acc[mt][nt], 0, 0, 0);
        __builtin_amdgcn_s_setprio(0);

        // ---- issue H'(kc+1) ----
        if (it < 31) {
#pragma unroll
            for (int j = 0; j < 4; j++)
                bfrH[j] = *(const bf16x8*)(gB + 8192 + j * 512);
            gB += 16384;
        }
    }

    // ---- ||u|| per row: reduce over 4 kd threads (consecutive lanes) ----
    sq += __shfl_xor(sq, 1, 64);
    sq += __shfl_xor(sq, 2, 64);
    if (kd == 0) invnh[row] = 1.0f / (sqrtf(sq) + 1e-8f * nb[bt * 4 + bb]);
    __syncthreads();

    // ---- epilogue: z = acc*invnh + b2; relu; q = sum(Wq*z) ----
    // C/D map (verified m74/m101): col = l&31, row = (r&3) + 8*(r>>2) + 4*(l>>5)
    float wqv[4], b2v[4];
#pragma unroll
    for (int nt = 0; nt < 4; nt++) {
        int o = wc * 128 + nt * 32 + l31;
        wqv[nt] = Wq[o]; b2v[nt] = b2[o];
    }
#pragma unroll
    for (int mt = 0; mt < 2; mt++) {
#pragma unroll
        for (int r = 0; r < 16; r++) {
            int R = mt * 32 + (r & 3) + 8 * (r >> 2) + 4 * hi;
            float inv = invnh[R];
            float qp = 0.f;
#pragma unroll
            for (int nt = 0; nt < 4; nt++) {
                float z = fmaf(acc[mt][nt][r], inv, b2v[nt]);
                z = fmaxf(z, 0.f);
                qp = fmaf(z, wqv[nt], qp);
            }
            qp += __shfl_xor(qp, 1, 64);
            qp += __shfl_xor(qp, 2, 64);
            qp += __shfl_xor(qp, 4, 64);
            qp += __shfl_xor(qp, 8, 64);
            qp += __shfl_xor(qp, 16, 64);
            if (l31 == 0) qred[R][wc] = qp;   // lane 0 (hi=0) and lane 32 (hi=1): different R
        }
    }
    __syncthreads();
    if (t < 64) {
        float qv = qred[t][0] + qred[t][1] + qred[t][2] + qred[t][3] + bq[0];
        int aa = at * 16 + (t >> 2);
        int bo = bt * 4 + (t & 3);
        out[(size_t)bo * NA + aa] = qv;
    }
}

extern "C" void kernel_launch(void* const* d_in, const int* in_sizes, int n_in,
                              void* d_out, int out_size, void* d_ws, size_t ws_size,
                              hipStream_t stream) {
    const float* states = (const float*)d_in[0];
    const float* W1     = (const float*)d_in[1];
    const float* b1     = (const float*)d_in[2];
    const float* W2     = (const float*)d_in[3];
    const float* b2     = (const float*)d_in[4];
    const float* Wq     = (const float*)d_in[5];
    const float* bq     = (const float*)d_in[6];
    float* out = (float*)d_out;

    char* ws = (char*)d_ws;
    unsigned short* Gt   = (unsigned short*)ws;                              // 8 MB
    unsigned short* W2f  = (unsigned short*)(ws + (8u << 20));               // 1 MB
    unsigned short* caT2 = (unsigned short*)(ws + (9u << 20));               // 128 KB
    float*          nbp  = (float*)(ws + (9u << 20) + (128u << 10));         // 16 KB

    knorm<<<NB, 64, 0, stream>>>(states, nbp);
    kprep<<<2304, 256, 0, stream>>>(W1, W2, W2f, caT2);
    kgemm1<<<1024, 256, 0, stream>>>(states, W1, b1, nbp, Gt);
    kmain<<<4096, 256, 0, stream>>>(Gt, caT2, W2f, nbp, b2, Wq, bq, out);
}

// Round 12
// 307.961 us; speedup vs baseline: 1.2230x; 1.2230x over previous
//
#include <hip/hip_runtime.h>
#include <stdint.h>

#define NB 4096
#define NS 512
#define NA 64
#define NH1 1024
#define NH2 512

typedef __attribute__((ext_vector_type(8))) short bf16x8;
typedef __attribute__((ext_vector_type(4))) float f32x4;

__device__ __forceinline__ unsigned short f2bf(float f) {
    union { float f; unsigned u; } v; v.f = f;
    return (unsigned short)((v.u + 0x8000u) >> 16);   // round-half-up bf16
}
__device__ __forceinline__ float bf2f(unsigned short h) {
    union { float f; unsigned u; } v; v.u = ((unsigned)h) << 16;
    return v.f;
}
__device__ __forceinline__ float bflo(unsigned u) {
    union { unsigned u; float f; } v; v.u = u << 16; return v.f;
}
__device__ __forceinline__ float bfhi(unsigned u) {
    union { unsigned u; float f; } v; v.u = u & 0xFFFF0000u; return v.f;
}
// truncating pack of two f32 -> bf16x2 (bias cancels in u/||u||): 1 v_perm
__device__ __forceinline__ unsigned packtrunc(float lo, float hi) {
    union { float f; unsigned u; } a, b; a.f = lo; b.f = hi;
    return __builtin_amdgcn_perm(b.u, a.u, 0x07060302u);
}
__device__ __forceinline__ void split2(float x, unsigned short& h, unsigned short& l) {
    unsigned short hh = f2bf(x);
    h = hh;
    l = f2bf(x - bf2f(hh));
}

// ---------------- P0: nb[b] = sqrt(||s_b||^2 + 1) + 1e-8 ----------------
__global__ void knorm(const float* __restrict__ S, float* __restrict__ nb) {
    int b = blockIdx.x; int l = threadIdx.x; // one wave
    const float* row = S + b * NS;
    float s = 0.f;
    for (int k = l; k < NS; k += 64) { float v = row[k]; s = fmaf(v, v, s); }
    for (int off = 32; off; off >>= 1) s += __shfl_down(s, off, 64);
    if (l == 0) nb[b] = sqrtf(s + 1.0f) + 1e-8f;
}

// ---------------- P1: W2f (R14 frag pack) + caT2 + NEW: W1 split-bf16 pack ----------------
// W2f short idx = ((kc*32 + c)*64 + l)*8 + j :
//   n = c*16 + (l>>2);  g = (l&3) ^ ((n>>1)&3);  value = W2[n][kc*32 + g*8 + j]
// caT2[at][kc][a_loc][kk] = W1[(kc*32+kk)*576 + 512 + at*16 + a_loc]
// NEW W1hf/W1lf[kc][n][kk] (kc 0..15, n 0..1023, kk 0..31): split-bf16 of
// W1[n*576 + kc*32 + kk]. Each 1 KB (n-16-group x 32k) block is read by one
// kgemm1 wave as a 16B-granule bijection -> fully coalesced direct B frags.
__global__ void kprep(const float* __restrict__ W1, const float* __restrict__ W2,
                      unsigned short* __restrict__ W2f, unsigned short* __restrict__ caT2,
                      unsigned short* __restrict__ W1hf, unsigned short* __restrict__ W1lf) {
    int i = blockIdx.x * 256 + threadIdx.x;
    if (i < 524288) {
        int j = i & 7; int l = (i >> 3) & 63; int c = (i >> 9) & 31; int kc = i >> 14;
        int n = c * 16 + (l >> 2);
        int g = (l & 3) ^ ((n >> 1) & 3);
        int k = kc * 32 + g * 8 + j;
        W2f[i] = f2bf(W2[(size_t)n * NH1 + k]);
    } else if (i < 589824) {
        int j2 = i - 524288;                 // 65536 entries
        int kk = j2 & 31; int a_loc = (j2 >> 5) & 15;
        int kc = (j2 >> 9) & 31; int att = j2 >> 14;
        int o = kc * 32 + kk;
        caT2[j2] = f2bf(W1[(size_t)o * 576 + 512 + att * 16 + a_loc]);
    } else {
        int i2 = i - 589824;                 // 524288 entries: W1 split pack
        int kk = i2 & 31; int n = (i2 >> 5) & 1023; int kc = i2 >> 15;
        float x = W1[(size_t)n * 576 + kc * 32 + kk];
        unsigned short h, l;
        split2(x, h, l);
        W1hf[i2] = h;
        W1lf[i2] = l;
    }
}

// ---------------- P2: Gt'[kc][b][32k] bf16 = s@W1s^T + b1*nb  (split-bf16, 3 GEMMs) ----
// R17: B operand now read DIRECTLY from precomputed W1hf/W1lf in global
// (L2-resident, 2 MB): removes the B half of split2 staging VALU and LDS.
// Same bf16 values (split2 in kprep), same MFMA order -> Gt BIT-IDENTICAL.
// 64x64 tiles, grid 1024 = 4 blocks/CU (R15 cross-block cover retained).
__global__ __launch_bounds__(256) void kgemm1(
        const float* __restrict__ Sm,
        const unsigned short* __restrict__ W1hf, const unsigned short* __restrict__ W1lf,
        const float* __restrict__ b1, const float* __restrict__ nb,
        unsigned short* __restrict__ Gt) {
    const int m0 = (blockIdx.x >> 4) * 64;   // 64 M-tiles
    const int n0 = (blockIdx.x & 15) * 64;   // 16 N-tiles
    __shared__ unsigned short Ah[64][40], Al[64][40];
    int t = threadIdx.x;
    int lane = t & 63, wave = t >> 6;
    int wr = wave >> 1, wc = wave & 1;       // 2x2 waves of 32x32 tiles
    int qd = lane >> 4, cl = lane & 15;
    int r = t >> 2, seg = t & 3;             // 4 threads/row, 8 floats each
    f32x4 acc[2][2] = {};

    // direct B frag source: (n0 + wc*32 + nt*16 + cl) * 32 + qd*8, += 32768/kc
    const unsigned short* gBh = W1hf + (size_t)(n0 + wc * 32 + cl) * 32 + qd * 8;
    const unsigned short* gBl = W1lf + (size_t)(n0 + wc * 32 + cl) * 32 + qd * 8;

    for (int k0 = 0; k0 < 512; k0 += 32) {
        {
            const float4* as4 = (const float4*)(Sm + (size_t)(m0 + r) * NS + k0 + seg * 8);
            unsigned* ah = (unsigned*)&Ah[r][seg * 8];
            unsigned* al = (unsigned*)&Al[r][seg * 8];
#pragma unroll
            for (int v = 0; v < 2; v++) {
                float4 fa = as4[v];
                unsigned short h0,h1,h2,h3,l0,l1,l2,l3;
                split2(fa.x,h0,l0); split2(fa.y,h1,l1); split2(fa.z,h2,l2); split2(fa.w,h3,l3);
                ah[v*2]   = (unsigned)h0 | ((unsigned)h1 << 16);
                ah[v*2+1] = (unsigned)h2 | ((unsigned)h3 << 16);
                al[v*2]   = (unsigned)l0 | ((unsigned)l1 << 16);
                al[v*2+1] = (unsigned)l2 | ((unsigned)l3 << 16);
            }
        }
        // B frags: issue before the barrier (independent of LDS); barrier's
        // vmcnt drain guarantees they land by MFMA time.
        bf16x8 b_h[2], b_l[2];
#pragma unroll
        for (int nt = 0; nt < 2; nt++) {
            b_h[nt] = *(const bf16x8*)(gBh + nt * 512);
            b_l[nt] = *(const bf16x8*)(gBl + nt * 512);
        }
        gBh += 32768;
        gBl += 32768;
        __syncthreads();
        bf16x8 a_h[2], a_l[2];
#pragma unroll
        for (int mt = 0; mt < 2; mt++) {
            a_h[mt] = *(const bf16x8*)&Ah[wr*32 + mt*16 + cl][qd*8];
            a_l[mt] = *(const bf16x8*)&Al[wr*32 + mt*16 + cl][qd*8];
        }
#pragma unroll
        for (int mt = 0; mt < 2; mt++)
#pragma unroll
            for (int nt = 0; nt < 2; nt++) {
                acc[mt][nt] = __builtin_amdgcn_mfma_f32_16x16x32_bf16(a_h[mt], b_h[nt], acc[mt][nt], 0, 0, 0);
                acc[mt][nt] = __builtin_amdgcn_mfma_f32_16x16x32_bf16(a_h[mt], b_l[nt], acc[mt][nt], 0, 0, 0);
                acc[mt][nt] = __builtin_amdgcn_mfma_f32_16x16x32_bf16(a_l[mt], b_h[nt], acc[mt][nt], 0, 0, 0);
            }
        __syncthreads();
    }
#pragma unroll
    for (int mt = 0; mt < 2; mt++)
#pragma unroll
        for (int i = 0; i < 4; i++) {
            int m = m0 + wr*32 + mt*16 + qd*4 + i;
            float nbv = nb[m];
#pragma unroll
            for (int nt = 0; nt < 2; nt++) {
                int n = n0 + wc*32 + nt*16 + cl;
                float val = fmaf(b1[n], nbv, acc[mt][nt][i]);
                Gt[((size_t)(n >> 5) * NB + m) * 32 + (n & 31)] = f2bf(val);
            }
        }
}

// ---------------- Main: 256 thr, 64 rows (16a x 4b) x 512 cols, K=1024, Kc=32 ----------
// R14 EXACT (reverted from R16's 32x32 experiment, which regressed 243->325:
// 8-MFMA clusters too short to cover paired L2 drains; pipe-busy time was
// unchanged but exposure grew). Best verified: 243 us, MfmaUtil ~51.5.
// 64-row 4-wave blocks, grid 4096, global-B bfrL/H register pipeline, As
// 8-slot ring with barrier every 4 iters (produce-lead 4).
__global__ __launch_bounds__(256, 2) void kmain(
        const unsigned short* __restrict__ Gt,    // [32][4096][32]
        const unsigned short* __restrict__ caT2,  // [4][32][16][32]
        const unsigned short* __restrict__ W2f,   // per-kc frag-packed tiles (32 KB each)
        const float* __restrict__ nb,
        const float* __restrict__ b2, const float* __restrict__ Wq,
        const float* __restrict__ bq, float* __restrict__ out) {
    int bid = blockIdx.x;
    int at = bid & 3;
    int bt = bid >> 2;            // 0..1023, covers b rows bt*4 .. bt*4+3

    __shared__ __align__(16) unsigned short As[8][64][40];  // 8-slot ring, 40 KB, pad +8
    __shared__ float invnh[64];
    __shared__ float qred[64][4];

    int t = threadIdx.x;          // 0..255
    int lane = t & 63, wc = t >> 6;   // wc = wave = col quarter
    int l15 = lane & 15, l4 = lane >> 4;

    // A-gen role: thread owns row (t>>2), k-octet (t&3); 8 elements/iter
    int row = t >> 2, kd = t & 3;     // row 0..63
    int ab = row >> 2, bb = row & 3;  // 16 a x 4 b
    const unsigned short* gG = Gt + ((size_t)(bt * 4 + bb)) * 32 + kd * 8;
    const unsigned short* gC = caT2 + (size_t)at * 16384 + ab * 32 + kd * 8;

    float sq = 0.f;
    f32x4 acc[4][8] = {};
    bf16x8 g_v, c_v;

    auto agen = [&](int slot) {
        const unsigned* gd = (const unsigned*)&g_v;
        const unsigned* cd = (const unsigned*)&c_v;
        unsigned ow[4];
#pragma unroll
        for (int p = 0; p < 4; p++) {
            float u0 = fmaxf(bflo(gd[p]) + bflo(cd[p]), 0.f);
            float u1 = fmaxf(bfhi(gd[p]) + bfhi(cd[p]), 0.f);
            sq = fmaf(u0, u0, sq);
            sq = fmaf(u1, u1, sq);
            ow[p] = packtrunc(u0, u1);
        }
        *(bf16x8*)&As[slot][row][kd * 8] = *(bf16x8*)ow;
    };

    // B frag source: de-swizzled per-lane global address, iter-invariant offset
    const int boff = (wc * 128 + l15) * 32 + ((l4 ^ ((l15 >> 1) & 3)) << 3);
    const unsigned short* gB = W2f + boff;

    bf16x8 bfrL[4], bfrH[4];

    // ---- prologue: produce tiles 0..3 into ring slots 0..3; leave g/c = tile 4 ----
    g_v = *(const bf16x8*)gG;
    c_v = *(const bf16x8*)gC;
#pragma unroll
    for (int p = 0; p < 4; ++p) {
        agen(p);                       // tile p -> slot p (ascending kc: sq order preserved)
        gG += (size_t)NB * 32;
        gC += 512;
        g_v = *(const bf16x8*)gG;      // tile p+1 (ends with tile 4)
        c_v = *(const bf16x8*)gC;
    }
    // bfr(kc0)
#pragma unroll
    for (int j = 0; j < 4; j++)
        bfrL[j] = *(const bf16x8*)(gB + j * 512);
#pragma unroll
    for (int j = 0; j < 4; j++)
        bfrH[j] = *(const bf16x8*)(gB + (4 + j) * 512);
    gB += 16384;

    for (int it = 0; it < 32; ++it) {
        // ---- window barrier: publish tiles produced in previous window ----
        if ((it & 3) == 0) {
            asm volatile("s_waitcnt lgkmcnt(0)" ::: "memory");  // drain own agen writes
            __builtin_amdgcn_s_barrier();
            __builtin_amdgcn_sched_barrier(0);
        }
        int rs = it & 7;

        // ---- A frags from ring slot ----
        bf16x8 af[4];
#pragma unroll
        for (int mt = 0; mt < 4; mt++)
            af[mt] = *(const bf16x8*)&As[rs][mt * 16 + l15][l4 * 8];

        // ---- produce tile it+4 into slot (it+4)&7; prefetch g/c(it+5) ----
        if (it < 28) agen((it + 4) & 7);
        if (it < 27) {
            gG += (size_t)NB * 32;
            gC += 512;
            g_v = *(const bf16x8*)gG;
            c_v = *(const bf16x8*)gC;
        }

        // ---- MFMA on L half (bfrH(kc) still draining under this) ----
        __builtin_amdgcn_s_setprio(1);
#pragma unroll
        for (int nt = 0; nt < 4; nt++)
#pragma unroll
            for (int mt = 0; mt < 4; mt++)
                acc[mt][nt] = __builtin_amdgcn_mfma_f32_16x16x32_bf16(af[mt], bfrL[nt], acc[mt][nt], 0, 0, 0);
        __builtin_amdgcn_s_setprio(0);

        // ---- issue L'(kc+1) into L regs (WAR reuse; drains under H MFMAs) ----
        if (it < 31) {
#pragma unroll
            for (int j = 0; j < 4; j++)
                bfrL[j] = *(const bf16x8*)(gB + j * 512);
        }

        // ---- MFMA on H half (L' draining under this) ----
        __builtin_amdgcn_s_setprio(1);
#pragma unroll
        for (int nt = 0; nt < 4; nt++)
#pragma unroll
            for (int mt = 0; mt < 4; mt++)
                acc[mt][4 + nt] = __builtin_amdgcn_mfma_f32_16x16x32_bf16(af[mt], bfrH[nt], acc[mt][4 + nt], 0, 0, 0);
        __builtin_amdgcn_s_setprio(0);

        // ---- issue H'(kc+1) ----
        if (it < 31) {
#pragma unroll
            for (int j = 0; j < 4; j++)
                bfrH[j] = *(const bf16x8*)(gB + (4 + j) * 512);
            gB += 16384;
        }
    }

    // ---- ||u|| per row: reduce over 4 kd threads (consecutive lanes) ----
    sq += __shfl_xor(sq, 1, 64);
    sq += __shfl_xor(sq, 2, 64);
    if (kd == 0) invnh[row] = 1.0f / (sqrtf(sq) + 1e-8f * nb[bt * 4 + bb]);
    __syncthreads();

    // ---- epilogue: z = acc*invnh + b2; relu; q = sum(Wq*z) ----
    float wqv[8], b2v[8];
#pragma unroll
    for (int nt = 0; nt < 8; nt++) {
        int o = wc * 128 + nt * 16 + l15;
        wqv[nt] = Wq[o]; b2v[nt] = b2[o];
    }
#pragma unroll
    for (int mt = 0; mt < 4; mt++) {
#pragma unroll
        for (int i = 0; i < 4; i++) {
            int R = mt * 16 + l4 * 4 + i;
            float inv = invnh[R];
            float qp = 0.f;
#pragma unroll
            for (int nt = 0; nt < 8; nt++) {
                float z = fmaf(acc[mt][nt][i], inv, b2v[nt]);
                z = fmaxf(z, 0.f);
                qp = fmaf(z, wqv[nt], qp);
            }
            qp += __shfl_xor(qp, 1, 64);
            qp += __shfl_xor(qp, 2, 64);
            qp += __shfl_xor(qp, 4, 64);
            qp += __shfl_xor(qp, 8, 64);
            if (l15 == 0) qred[R][wc] = qp;
        }
    }
    __syncthreads();
    if (t < 64) {
        float qv = qred[t][0] + qred[t][1] + qred[t][2] + qred[t][3] + bq[0];
        int aa = at * 16 + (t >> 2);
        int bo = bt * 4 + (t & 3);
        out[(size_t)bo * NA + aa] = qv;
    }
}

extern "C" void kernel_launch(void* const* d_in, const int* in_sizes, int n_in,
                              void* d_out, int out_size, void* d_ws, size_t ws_size,
                              hipStream_t stream) {
    const float* states = (const float*)d_in[0];
    const float* W1     = (const float*)d_in[1];
    const float* b1     = (const float*)d_in[2];
    const float* W2     = (const float*)d_in[3];
    const float* b2     = (const float*)d_in[4];
    const float* Wq     = (const float*)d_in[5];
    const float* bq     = (const float*)d_in[6];
    float* out = (float*)d_out;

    char* ws = (char*)d_ws;
    unsigned short* Gt   = (unsigned short*)ws;                              // 8 MB
    unsigned short* W2f  = (unsigned short*)(ws + (8u << 20));               // 1 MB
    unsigned short* caT2 = (unsigned short*)(ws + (9u << 20));               // 128 KB
    float*          nbp  = (float*)(ws + (9u << 20) + (128u << 10));         // 16 KB
    unsigned short* W1hf = (unsigned short*)(ws + (9u << 20) + (256u << 10)); // 1 MB
    unsigned short* W1lf = (unsigned short*)(ws + (10u << 20) + (256u << 10)); // 1 MB

    knorm<<<NB, 64, 0, stream>>>(states, nbp);
    kprep<<<4352, 256, 0, stream>>>(W1, W2, W2f, caT2, W1hf, W1lf);
    kgemm1<<<1024, 256, 0, stream>>>(states, W1hf, W1lf, b1, nbp, Gt);
    kmain<<<4096, 256, 0, stream>>>(Gt, caT2, W2f, nbp, b2, Wq, bq, out);
}